// Round 6
// baseline (352.274 us; speedup 1.0000x reference)
//
#include <hip/hip_runtime.h>

#define L_SEQ 4096
#define DM    1024
#define NH    16
#define HD    64

typedef unsigned short ushort_t;
typedef __attribute__((ext_vector_type(8))) short bf16x8;
typedef __attribute__((ext_vector_type(4))) float f32x4;

__device__ inline unsigned short f2bf(float f) {
    union { float f; unsigned int u; } v; v.f = f;
    unsigned int r = v.u + 0x7fffu + ((v.u >> 16) & 1u);
    return (unsigned short)(r >> 16);
}

// async global->LDS, 16B/lane. LDS dest = wave-uniform base + lane*16.
__device__ inline void load_lds16(const ushort_t* g, ushort_t* l) {
    __builtin_amdgcn_global_load_lds(
        (const __attribute__((address_space(1))) unsigned int*)g,
        (__attribute__((address_space(3))) unsigned int*)l, 16, 0, 0);
}

// ---------------------------------------------------------------------------
// Runtime input-dtype detection (bf16 vs fp32 global buffers). Verified R3.
// ---------------------------------------------------------------------------
__device__ inline bool detect_f32(const ushort_t* xraw) {
    __shared__ int s_flag;
    const int t = threadIdx.x;
    if (t < 64) {
        unsigned e = (xraw[2 * t] >> 7) & 0xFFu;
        unsigned long long m = __ballot(e >= 0x88u);
        if (t == 0) s_flag = (__popcll(m) >= 8) ? 1 : 0;
    }
    __syncthreads();
    return s_flag != 0;
}

// ---------------------------------------------------------------------------
// x -> bf16 canonical buffer (4M elems, 8 elems/thread)
// ---------------------------------------------------------------------------
__global__ __launch_bounds__(256) void convert_x(const void* __restrict__ xv,
                                                 ushort_t* __restrict__ xb) {
    bool f32 = detect_f32((const ushort_t*)xv);
    const int i = (blockIdx.x * 256 + threadIdx.x) * 8;
    if (f32) {
        const float* xf = (const float*)xv;
        float4 v0 = *(const float4*)(xf + i);
        float4 v1 = *(const float4*)(xf + i + 4);
        ushort_t pk[8] = {f2bf(v0.x), f2bf(v0.y), f2bf(v0.z), f2bf(v0.w),
                          f2bf(v1.x), f2bf(v1.y), f2bf(v1.z), f2bf(v1.w)};
        *(uint4*)(xb + i) = *(const uint4*)pk;
    } else {
        *(uint4*)(xb + i) = *(const uint4*)((const ushort_t*)xv + i);
    }
}

// ---------------------------------------------------------------------------
// weights -> bf16 TRANSPOSED wT[n][k] (z picks which of 4 weights)
// ---------------------------------------------------------------------------
__global__ __launch_bounds__(256) void convert_wt(const void* __restrict__ xdet,
                                                  const void* __restrict__ w0,
                                                  const void* __restrict__ w1,
                                                  const void* __restrict__ w2,
                                                  const void* __restrict__ w3,
                                                  ushort_t* __restrict__ wT) {
    bool f32 = detect_f32((const ushort_t*)xdet);
    const int z = blockIdx.z;
    const void* w = (z == 0) ? w0 : (z == 1) ? w1 : (z == 2) ? w2 : w3;
    ushort_t* out = wT + (size_t)z * (DM * DM);
    __shared__ ushort_t T[64][65];
    const int k0 = blockIdx.x * 64, n0 = blockIdx.y * 64;
    const int t = threadIdx.x;
    #pragma unroll
    for (int i = 0; i < 16; ++i) {
        int e = t + i * 256;
        int r = e >> 6, c = e & 63;
        T[r][c] = f32 ? f2bf(((const float*)w)[(size_t)(k0 + r) * DM + n0 + c])
                      : ((const ushort_t*)w)[(size_t)(k0 + r) * DM + n0 + c];
    }
    __syncthreads();
    #pragma unroll
    for (int i = 0; i < 16; ++i) {
        int e = t + i * 256;
        int d = e >> 6, l = e & 63;
        out[(size_t)(n0 + d) * DM + k0 + l] = T[l][d];
    }
}

// ---------------------------------------------------------------------------
// m97-structure GEMM: C[M,1024] = A[M,1024] * Bt[1024,1024]^T (Bt is [n][k]).
// 128x128 tile, BK=32, 256 thr. Both operands staged via global_load_lds x16.
// ---------------------------------------------------------------------------
__device__ inline void gemm128_body(const ushort_t* __restrict__ A,
                                    const ushort_t* __restrict__ Bt,
                                    void* __restrict__ Cv, bool c_f32) {
    constexpr int K = 1024, NOUT = 1024;
    __shared__ ushort_t As[128 * 32];
    __shared__ ushort_t Bs[128 * 32];

    const int t = threadIdx.x, lane = t & 63, wave = t >> 6;
    const int l15 = lane & 15, quad = lane >> 4;
    const int m0 = blockIdx.y * 128, n0 = blockIdx.x * 128;
    const int mw = (wave >> 1) * 64, nw = (wave & 1) * 64;
    const int srow = lane >> 2, scol = (lane & 3) * 8;

    f32x4 acc[4][4] = {};

    for (int k0 = 0; k0 < K; k0 += 32) {
        #pragma unroll
        for (int j = 0; j < 2; ++j) {
            const int r0 = wave * 32 + j * 16;
            load_lds16(A  + (size_t)(m0 + r0 + srow) * K + k0 + scol, &As[r0 * 32]);
            load_lds16(Bt + (size_t)(n0 + r0 + srow) * K + k0 + scol, &Bs[r0 * 32]);
        }
        __syncthreads();

        bf16x8 af[4], bf[4];
        #pragma unroll
        for (int i = 0; i < 4; ++i) {
            af[i] = *(const bf16x8*)&As[(mw + i * 16 + l15) * 32 + quad * 8];
            bf[i] = *(const bf16x8*)&Bs[(nw + i * 16 + l15) * 32 + quad * 8];
        }
        #pragma unroll
        for (int mt = 0; mt < 4; ++mt)
            #pragma unroll
            for (int nt = 0; nt < 4; ++nt)
                acc[mt][nt] = __builtin_amdgcn_mfma_f32_16x16x32_bf16(af[mt], bf[nt], acc[mt][nt], 0, 0, 0);

        __syncthreads();
    }

    ushort_t* Ch = (ushort_t*)Cv;
    float*    Cf = (float*)Cv;
    #pragma unroll
    for (int mt = 0; mt < 4; ++mt)
        #pragma unroll
        for (int nt = 0; nt < 4; ++nt)
            #pragma unroll
            for (int r = 0; r < 4; ++r) {
                int row = m0 + mw + mt * 16 + quad * 4 + r;
                int col = n0 + nw + nt * 16 + l15;
                if (c_f32) Cf[(size_t)row * NOUT + col] = acc[mt][nt][r];
                else       Ch[(size_t)row * NOUT + col] = f2bf(acc[mt][nt][r]);
            }
}

__global__ __launch_bounds__(256) void qkv128(const ushort_t* __restrict__ xb,
                                              const ushort_t* __restrict__ wT,
                                              ushort_t* Qp, ushort_t* Kp, ushort_t* Vp) {
    const int z = blockIdx.z;
    const ushort_t* Bt = wT + (size_t)z * (DM * DM);
    ushort_t* C = (z == 0) ? Qp : (z == 1) ? Kp : Vp;
    gemm128_body(xb, Bt, C, false);
}

__global__ __launch_bounds__(256) void ogemm128(const void* __restrict__ xdet,
                                                const ushort_t* __restrict__ An,
                                                const ushort_t* __restrict__ woT,
                                                void* __restrict__ C) {
    bool f32 = detect_f32((const ushort_t*)xdet);
    gemm128_body(An, woT, C, f32);
}

// ---------------------------------------------------------------------------
// V transpose: Vp[L][DM] -> Vt[DM][L]
// ---------------------------------------------------------------------------
__global__ __launch_bounds__(256) void transpose_kernel(const ushort_t* __restrict__ Vp,
                                                        ushort_t* __restrict__ Vt) {
    __shared__ ushort_t T[64][65];
    const int l0 = blockIdx.x * 64, d0 = blockIdx.y * 64;
    const int t  = threadIdx.x;
    #pragma unroll
    for (int i = 0; i < 16; ++i) {
        int e = t + i * 256;
        int r = e >> 6, c = e & 63;
        T[r][c] = Vp[(size_t)(l0 + r) * DM + d0 + c];
    }
    __syncthreads();
    #pragma unroll
    for (int i = 0; i < 16; ++i) {
        int e = t + i * 256;
        int d = e >> 6, l = e & 63;
        Vt[(size_t)(d0 + d) * L_SEQ + l0 + l] = T[l][d];
    }
}

// ---------------------------------------------------------------------------
// Flash attention, S^T formulation, FIXED-MAX softmax (scores bounded:
// qk*c0 <= ~9 in log2 domain, ALiBi <= 0 -> constant max FM=20 is safe;
// normalization at the epilogue makes the result exact modulo fp).
// Block = ONE 64-q-tile x 1 head (grid 64x16 = 1024, reversed: big qb
// first). Main loop is mask-free; the diag stage (provably the last one)
// is split out with block-uniform dead-chunk skipping.
// ---------------------------------------------------------------------------
__global__ __launch_bounds__(256) void attn_kernel(const ushort_t* __restrict__ Q,
                                                   const ushort_t* __restrict__ Kp,
                                                   const ushort_t* __restrict__ Vt,
                                                   ushort_t* __restrict__ O) {
    __shared__ ushort_t Ks[128][72];
    __shared__ ushort_t Vs[64][136];
    __shared__ ushort_t Pt[64][136];

    const int h    = blockIdx.y;
    const int qb   = (int)gridDim.x - 1 - (int)blockIdx.x;  // big tiles first
    const int q0   = qb * 64;
    const int t    = threadIdx.x;
    const int lane = t & 63, wave = t >> 6;
    const int l15  = lane & 15, quad = lane >> 4;
    const float LOG2E  = 1.44269504f;
    const float slope2 = exp2f(-0.5f * (float)(h + 1)) * LOG2E;
    const float c0     = 0.125f * LOG2E;
    const float FM     = 20.0f;          // fixed softmax max (log2 domain)
    const int   qg     = q0 + wave * 16 + l15;   // this lane's query row
    const float qf     = (float)qg;
    const float qd4f   = (float)(quad * 4);

    // per-(r) alibi offsets, constant per block
    float sr[4];
    #pragma unroll
    for (int r = 0; r < 4; ++r) sr[r] = slope2 * (float)r;

    bf16x8 bq[2];
    #pragma unroll
    for (int kt = 0; kt < 2; ++kt)
        bq[kt] = *(const bf16x8*)(Q + (size_t)qg * DM + h * HD + kt * 32 + quad * 8);

    f32x4 acc_o[4] = {};
    float lsum[4] = {0.f, 0.f, 0.f, 0.f};   // per-lane partial row sums (ILP x4)

    const int nst = (qb + 2) >> 1;           // last stage is the diag one
    for (int s = 0; s < nst; ++s) {
        const int kv0 = s * 128;
        __syncthreads();
        #pragma unroll
        for (int i = 0; i < 4; ++i) {
            int idx = t + i * 256;
            int r = idx >> 3, c = (idx & 7) * 8;
            *(uint4*)&Ks[r][c] = *(const uint4*)(Kp + (size_t)(kv0 + r) * DM + h * HD + c);
        }
        #pragma unroll
        for (int i = 0; i < 4; ++i) {
            int idx = t + i * 256;
            int d = idx >> 4, c = (idx & 15) * 8;
            *(uint4*)&Vs[d][c] = *(const uint4*)(Vt + (size_t)(h * HD + d) * L_SEQ + kv0 + c);
        }
        __syncthreads();

        // S^T[kv][q]: A = K (m=kv), B = Q (n=q). Lane: q=l15, kv=mt*16+quad*4+r
        f32x4 sacc[8];
        #pragma unroll
        for (int mt = 0; mt < 8; ++mt) sacc[mt] = (f32x4){0.f, 0.f, 0.f, 0.f};
        #pragma unroll
        for (int kt = 0; kt < 2; ++kt)
            #pragma unroll
            for (int mt = 0; mt < 8; ++mt) {
                bf16x8 a = *(const bf16x8*)&Ks[mt * 16 + l15][kt * 32 + quad * 8];
                sacc[mt] = __builtin_amdgcn_mfma_f32_16x16x32_bf16(a, bq[kt], sacc[mt], 0, 0, 0);
            }

        const float off = fmaf(slope2, (float)kv0 + qd4f - qf, -FM);
        if (s < nst - 1) {
            // mask-free main path: p = exp2(qk*c0 + alibi - FM)
            #pragma unroll
            for (int mt = 0; mt < 8; ++mt) {
                const float base = fmaf(slope2, (float)(mt * 16), off);
                #pragma unroll
                for (int r = 0; r < 4; ++r) {
                    float p = exp2f(fmaf(sacc[mt][r], c0, base + sr[r]));
                    sacc[mt][r] = p;
                    lsum[r] += p;
                }
            }
        } else {
            // diag stage: block-uniform skip of fully-masked 16-kv chunks
            const int qmax = q0 + 63;
            #pragma unroll
            for (int mt = 0; mt < 8; ++mt) {
                if (kv0 + mt * 16 <= qmax) {
                    const float base = fmaf(slope2, (float)(mt * 16), off);
                    #pragma unroll
                    for (int r = 0; r < 4; ++r) {
                        int kvg = kv0 + mt * 16 + quad * 4 + r;
                        float p = (kvg <= qg)
                                ? exp2f(fmaf(sacc[mt][r], c0, base + sr[r]))
                                : 0.f;
                        sacc[mt][r] = p;
                        lsum[r] += p;
                    }
                } else {
                    sacc[mt] = (f32x4){0.f, 0.f, 0.f, 0.f};
                }
            }
        }

        // pack P^T -> Pt[q][kv] (b64 truncation pack; zeros for masked)
        #pragma unroll
        for (int mt = 0; mt < 8; ++mt) {
            union { float f; unsigned u; } a0, a1, a2, a3;
            a0.f = sacc[mt][0]; a1.f = sacc[mt][1];
            a2.f = sacc[mt][2]; a3.f = sacc[mt][3];
            uint2 w;
            w.x = __builtin_amdgcn_perm(a1.u, a0.u, 0x07060302);
            w.y = __builtin_amdgcn_perm(a3.u, a2.u, 0x07060302);
            *(uint2*)&Pt[wave * 16 + l15][mt * 16 + quad * 4] = w;
        }
        __threadfence_block();

        // O += P·V: A = Pt[q][kv], B = Vs[d][kv]
        #pragma unroll
        for (int kt = 0; kt < 4; ++kt) {
            bf16x8 a = *(const bf16x8*)&Pt[wave * 16 + l15][kt * 32 + quad * 8];
            #pragma unroll
            for (int nt = 0; nt < 4; ++nt) {
                bf16x8 b = *(const bf16x8*)&Vs[nt * 16 + l15][kt * 32 + quad * 8];
                acc_o[nt] = __builtin_amdgcn_mfma_f32_16x16x32_bf16(a, b, acc_o[nt], 0, 0, 0);
            }
        }
    }

    // epilogue: one cross-lane l reduction per block
    float l_r = (lsum[0] + lsum[1]) + (lsum[2] + lsum[3]);
    l_r += __shfl_xor(l_r, 16);
    l_r += __shfl_xor(l_r, 32);
    float linv[4];
    #pragma unroll
    for (int r = 0; r < 4; ++r) linv[r] = 1.0f / __shfl(l_r, quad * 4 + r);
    #pragma unroll
    for (int nt = 0; nt < 4; ++nt)
        #pragma unroll
        for (int r = 0; r < 4; ++r) {
            int row = q0 + wave * 16 + quad * 4 + r;
            O[(size_t)row * DM + h * HD + nt * 16 + l15] = f2bf(acc_o[nt][r] * linv[r]);
        }
}

// ---------------------------------------------------------------------------
extern "C" void kernel_launch(void* const* d_in, const int* in_sizes, int n_in,
                              void* d_out, int out_size, void* d_ws, size_t ws_size,
                              hipStream_t stream) {
    const void* x  = d_in[0];
    const void* wq = d_in[1];
    const void* wk = d_in[2];
    const void* wv = d_in[3];
    const void* wo = d_in[4];

    const size_t SZ = (size_t)L_SEQ * DM;   // 4M elems
    const size_t WZ = (size_t)DM * DM;      // 1M elems
    ushort_t* xb = (ushort_t*)d_ws;         // 8 MB
    ushort_t* wT = xb + SZ;                 // 4 x 2 MB
    ushort_t* Qp = wT + 4 * WZ;             // 8 MB
    ushort_t* Kp = Qp + SZ;                 // 8 MB
    ushort_t* Vp = Kp + SZ;                 // 8 MB
    ushort_t* Vt = Vp + SZ;                 // 8 MB  -> total 48 MB
    ushort_t* An = xb;                      // xb dead after qkv -> safe alias

    convert_x<<<2048, 256, 0, stream>>>(x, xb);
    convert_wt<<<dim3(16, 16, 4), 256, 0, stream>>>(x, wq, wk, wv, wo, wT);
    qkv128<<<dim3(DM / 128, L_SEQ / 128, 3), 256, 0, stream>>>(xb, wT, Qp, Kp, Vp);
    transpose_kernel<<<dim3(L_SEQ / 64, DM / 64), 256, 0, stream>>>(Vp, Vt);
    attn_kernel<<<dim3(64, NH), 256, 0, stream>>>(Qp, Kp, Vt, An);
    ogemm128<<<dim3(DM / 128, L_SEQ / 128), 256, 0, stream>>>(x, An, wT + 3 * WZ, d_out);
}

// Round 7
// 336.450 us; speedup vs baseline: 1.0470x; 1.0470x over previous
//
#include <hip/hip_runtime.h>

#define L_SEQ 4096
#define DM    1024
#define NH    16
#define HD    64

typedef unsigned short ushort_t;
typedef __attribute__((ext_vector_type(8))) short bf16x8;
typedef __attribute__((ext_vector_type(4))) float f32x4;

__device__ inline unsigned short f2bf(float f) {
    union { float f; unsigned int u; } v; v.f = f;
    unsigned int r = v.u + 0x7fffu + ((v.u >> 16) & 1u);
    return (unsigned short)(r >> 16);
}

// async global->LDS, 16B/lane. LDS dest = wave-uniform base + lane*16.
__device__ inline void load_lds16(const ushort_t* g, ushort_t* l) {
    __builtin_amdgcn_global_load_lds(
        (const __attribute__((address_space(1))) unsigned int*)g,
        (__attribute__((address_space(3))) unsigned int*)l, 16, 0, 0);
}

// ---------------------------------------------------------------------------
// Runtime input-dtype detection (bf16 vs fp32 global buffers). Verified R3.
// ---------------------------------------------------------------------------
__device__ inline bool detect_f32(const ushort_t* xraw) {
    __shared__ int s_flag;
    const int t = threadIdx.x;
    if (t < 64) {
        unsigned e = (xraw[2 * t] >> 7) & 0xFFu;
        unsigned long long m = __ballot(e >= 0x88u);
        if (t == 0) s_flag = (__popcll(m) >= 8) ? 1 : 0;
    }
    __syncthreads();
    return s_flag != 0;
}

// ---------------------------------------------------------------------------
// x -> bf16 canonical buffer (4M elems, 8 elems/thread)
// ---------------------------------------------------------------------------
__global__ __launch_bounds__(256) void convert_x(const void* __restrict__ xv,
                                                 ushort_t* __restrict__ xb) {
    bool f32 = detect_f32((const ushort_t*)xv);
    const int i = (blockIdx.x * 256 + threadIdx.x) * 8;
    if (f32) {
        const float* xf = (const float*)xv;
        float4 v0 = *(const float4*)(xf + i);
        float4 v1 = *(const float4*)(xf + i + 4);
        ushort_t pk[8] = {f2bf(v0.x), f2bf(v0.y), f2bf(v0.z), f2bf(v0.w),
                          f2bf(v1.x), f2bf(v1.y), f2bf(v1.z), f2bf(v1.w)};
        *(uint4*)(xb + i) = *(const uint4*)pk;
    } else {
        *(uint4*)(xb + i) = *(const uint4*)((const ushort_t*)xv + i);
    }
}

// ---------------------------------------------------------------------------
// weights -> bf16 TRANSPOSED wT[n][k] (z picks which of 4 weights)
// ---------------------------------------------------------------------------
__global__ __launch_bounds__(256) void convert_wt(const void* __restrict__ xdet,
                                                  const void* __restrict__ w0,
                                                  const void* __restrict__ w1,
                                                  const void* __restrict__ w2,
                                                  const void* __restrict__ w3,
                                                  ushort_t* __restrict__ wT) {
    bool f32 = detect_f32((const ushort_t*)xdet);
    const int z = blockIdx.z;
    const void* w = (z == 0) ? w0 : (z == 1) ? w1 : (z == 2) ? w2 : w3;
    ushort_t* out = wT + (size_t)z * (DM * DM);
    __shared__ ushort_t T[64][65];
    const int k0 = blockIdx.x * 64, n0 = blockIdx.y * 64;
    const int t = threadIdx.x;
    #pragma unroll
    for (int i = 0; i < 16; ++i) {
        int e = t + i * 256;
        int r = e >> 6, c = e & 63;
        T[r][c] = f32 ? f2bf(((const float*)w)[(size_t)(k0 + r) * DM + n0 + c])
                      : ((const ushort_t*)w)[(size_t)(k0 + r) * DM + n0 + c];
    }
    __syncthreads();
    #pragma unroll
    for (int i = 0; i < 16; ++i) {
        int e = t + i * 256;
        int d = e >> 6, l = e & 63;
        out[(size_t)(n0 + d) * DM + k0 + l] = T[l][d];
    }
}

// ---------------------------------------------------------------------------
// m97-structure GEMM: C[M,1024] = A[M,1024] * Bt[1024,1024]^T (Bt is [n][k]).
// 128x128 tile, BK=32, 256 thr. Both operands staged via global_load_lds x16.
// ---------------------------------------------------------------------------
__device__ inline void gemm128_body(const ushort_t* __restrict__ A,
                                    const ushort_t* __restrict__ Bt,
                                    void* __restrict__ Cv, bool c_f32) {
    constexpr int K = 1024, NOUT = 1024;
    __shared__ ushort_t As[128 * 32];
    __shared__ ushort_t Bs[128 * 32];

    const int t = threadIdx.x, lane = t & 63, wave = t >> 6;
    const int l15 = lane & 15, quad = lane >> 4;
    const int m0 = blockIdx.y * 128, n0 = blockIdx.x * 128;
    const int mw = (wave >> 1) * 64, nw = (wave & 1) * 64;
    const int srow = lane >> 2, scol = (lane & 3) * 8;

    f32x4 acc[4][4] = {};

    for (int k0 = 0; k0 < K; k0 += 32) {
        #pragma unroll
        for (int j = 0; j < 2; ++j) {
            const int r0 = wave * 32 + j * 16;
            load_lds16(A  + (size_t)(m0 + r0 + srow) * K + k0 + scol, &As[r0 * 32]);
            load_lds16(Bt + (size_t)(n0 + r0 + srow) * K + k0 + scol, &Bs[r0 * 32]);
        }
        __syncthreads();

        bf16x8 af[4], bf[4];
        #pragma unroll
        for (int i = 0; i < 4; ++i) {
            af[i] = *(const bf16x8*)&As[(mw + i * 16 + l15) * 32 + quad * 8];
            bf[i] = *(const bf16x8*)&Bs[(nw + i * 16 + l15) * 32 + quad * 8];
        }
        #pragma unroll
        for (int mt = 0; mt < 4; ++mt)
            #pragma unroll
            for (int nt = 0; nt < 4; ++nt)
                acc[mt][nt] = __builtin_amdgcn_mfma_f32_16x16x32_bf16(af[mt], bf[nt], acc[mt][nt], 0, 0, 0);

        __syncthreads();
    }

    ushort_t* Ch = (ushort_t*)Cv;
    float*    Cf = (float*)Cv;
    #pragma unroll
    for (int mt = 0; mt < 4; ++mt)
        #pragma unroll
        for (int nt = 0; nt < 4; ++nt)
            #pragma unroll
            for (int r = 0; r < 4; ++r) {
                int row = m0 + mw + mt * 16 + quad * 4 + r;
                int col = n0 + nw + nt * 16 + l15;
                if (c_f32) Cf[(size_t)row * NOUT + col] = acc[mt][nt][r];
                else       Ch[(size_t)row * NOUT + col] = f2bf(acc[mt][nt][r]);
            }
}

__global__ __launch_bounds__(256) void qkv128(const ushort_t* __restrict__ xb,
                                              const ushort_t* __restrict__ wT,
                                              ushort_t* Qp, ushort_t* Kp, ushort_t* Vp) {
    const int z = blockIdx.z;
    const ushort_t* Bt = wT + (size_t)z * (DM * DM);
    ushort_t* C = (z == 0) ? Qp : (z == 1) ? Kp : Vp;
    gemm128_body(xb, Bt, C, false);
}

__global__ __launch_bounds__(256) void ogemm128(const void* __restrict__ xdet,
                                                const ushort_t* __restrict__ An,
                                                const ushort_t* __restrict__ woT,
                                                void* __restrict__ C) {
    bool f32 = detect_f32((const ushort_t*)xdet);
    gemm128_body(An, woT, C, f32);
}

// ---------------------------------------------------------------------------
// V transpose: Vp[L][DM] -> Vt[DM][L]
// ---------------------------------------------------------------------------
__global__ __launch_bounds__(256) void transpose_kernel(const ushort_t* __restrict__ Vp,
                                                        ushort_t* __restrict__ Vt) {
    __shared__ ushort_t T[64][65];
    const int l0 = blockIdx.x * 64, d0 = blockIdx.y * 64;
    const int t  = threadIdx.x;
    #pragma unroll
    for (int i = 0; i < 16; ++i) {
        int e = t + i * 256;
        int r = e >> 6, c = e & 63;
        T[r][c] = Vp[(size_t)(l0 + r) * DM + d0 + c];
    }
    __syncthreads();
    #pragma unroll
    for (int i = 0; i < 16; ++i) {
        int e = t + i * 256;
        int d = e >> 6, l = e & 63;
        Vt[(size_t)(d0 + d) * L_SEQ + l0 + l] = T[l][d];
    }
}

// ---------------------------------------------------------------------------
// Flash attention, S^T formulation. UNIFORM PAIRED blocks (R5 structure,
// verified best): block = complementary q-tiles (63-bx, bx) x 1 head =
// exactly 33 stages per block, 512 blocks = exactly 2/CU, zero variance.
// Per-stage softmax from R6 (verified +23% per-wave MFMA density):
// fixed-max (scores bounded: qk*c0 <= ~9 log2, ALiBi <= 0 -> FM=20 safe;
// epilogue normalization makes it exact modulo fp), deferred l-reduction,
// mask-free main loop with diag stage split per half.
// ---------------------------------------------------------------------------
__global__ __launch_bounds__(256) void attn_kernel(const ushort_t* __restrict__ Q,
                                                   const ushort_t* __restrict__ Kp,
                                                   const ushort_t* __restrict__ Vt,
                                                   ushort_t* __restrict__ O) {
    __shared__ ushort_t Ks[128][72];
    __shared__ ushort_t Vs[64][136];
    __shared__ ushort_t Pt[64][136];

    const int h    = blockIdx.y;
    const int bx   = blockIdx.x;               // 0..31
    const int t    = threadIdx.x;
    const int lane = t & 63, wave = t >> 6;
    const int l15  = lane & 15, quad = lane >> 4;
    const float LOG2E  = 1.44269504f;
    const float slope2 = exp2f(-0.5f * (float)(h + 1)) * LOG2E;
    const float c0     = 0.125f * LOG2E;
    const float FM     = 20.0f;               // fixed softmax max (log2 domain)
    const float qd4f   = (float)(quad * 4);

    float sr[4];
    #pragma unroll
    for (int r = 0; r < 4; ++r) sr[r] = slope2 * (float)r;

    #pragma unroll
    for (int half = 0; half < 2; ++half) {
        const int qb = half ? bx : (63 - bx);
        const int q0 = qb * 64;
        const int qg = q0 + wave * 16 + l15;   // this lane's query row
        const float qf = (float)qg;

        bf16x8 bq[2];
        #pragma unroll
        for (int kt = 0; kt < 2; ++kt)
            bq[kt] = *(const bf16x8*)(Q + (size_t)qg * DM + h * HD + kt * 32 + quad * 8);

        f32x4 acc_o[4] = {};
        float lsum[4] = {0.f, 0.f, 0.f, 0.f};

        const int nst = (qb + 2) >> 1;         // last stage is the diag one
        for (int s = 0; s < nst; ++s) {
            const int kv0 = s * 128;
            __syncthreads();
            #pragma unroll
            for (int i = 0; i < 4; ++i) {
                int idx = t + i * 256;
                int r = idx >> 3, c = (idx & 7) * 8;
                *(uint4*)&Ks[r][c] = *(const uint4*)(Kp + (size_t)(kv0 + r) * DM + h * HD + c);
            }
            #pragma unroll
            for (int i = 0; i < 4; ++i) {
                int idx = t + i * 256;
                int d = idx >> 4, c = (idx & 15) * 8;
                *(uint4*)&Vs[d][c] = *(const uint4*)(Vt + (size_t)(h * HD + d) * L_SEQ + kv0 + c);
            }
            __syncthreads();

            // S^T[kv][q]: A = K (m=kv), B = Q (n=q). Lane: q=l15, kv=mt*16+quad*4+r
            f32x4 sacc[8];
            #pragma unroll
            for (int mt = 0; mt < 8; ++mt) sacc[mt] = (f32x4){0.f, 0.f, 0.f, 0.f};
            #pragma unroll
            for (int kt = 0; kt < 2; ++kt)
                #pragma unroll
                for (int mt = 0; mt < 8; ++mt) {
                    bf16x8 a = *(const bf16x8*)&Ks[mt * 16 + l15][kt * 32 + quad * 8];
                    sacc[mt] = __builtin_amdgcn_mfma_f32_16x16x32_bf16(a, bq[kt], sacc[mt], 0, 0, 0);
                }

            const float off = fmaf(slope2, (float)kv0 + qd4f - qf, -FM);
            if (s < nst - 1) {
                // mask-free main path: p = exp2(qk*c0 + alibi - FM)
                #pragma unroll
                for (int mt = 0; mt < 8; ++mt) {
                    const float base = fmaf(slope2, (float)(mt * 16), off);
                    #pragma unroll
                    for (int r = 0; r < 4; ++r) {
                        float p = exp2f(fmaf(sacc[mt][r], c0, base + sr[r]));
                        sacc[mt][r] = p;
                        lsum[r] += p;
                    }
                }
            } else {
                // diag stage: block-uniform skip of fully-masked 16-kv chunks
                const int qmax = q0 + 63;
                #pragma unroll
                for (int mt = 0; mt < 8; ++mt) {
                    if (kv0 + mt * 16 <= qmax) {
                        const float base = fmaf(slope2, (float)(mt * 16), off);
                        #pragma unroll
                        for (int r = 0; r < 4; ++r) {
                            int kvg = kv0 + mt * 16 + quad * 4 + r;
                            float p = (kvg <= qg)
                                    ? exp2f(fmaf(sacc[mt][r], c0, base + sr[r]))
                                    : 0.f;
                            sacc[mt][r] = p;
                            lsum[r] += p;
                        }
                    } else {
                        sacc[mt] = (f32x4){0.f, 0.f, 0.f, 0.f};
                    }
                }
            }

            // pack P^T -> Pt[q][kv] (b64 truncation pack; zeros for masked)
            #pragma unroll
            for (int mt = 0; mt < 8; ++mt) {
                union { float f; unsigned u; } a0, a1, a2, a3;
                a0.f = sacc[mt][0]; a1.f = sacc[mt][1];
                a2.f = sacc[mt][2]; a3.f = sacc[mt][3];
                uint2 w;
                w.x = __builtin_amdgcn_perm(a1.u, a0.u, 0x07060302);
                w.y = __builtin_amdgcn_perm(a3.u, a2.u, 0x07060302);
                *(uint2*)&Pt[wave * 16 + l15][mt * 16 + quad * 4] = w;
            }
            __threadfence_block();

            // O += P·V: A = Pt[q][kv], B = Vs[d][kv]
            #pragma unroll
            for (int kt = 0; kt < 4; ++kt) {
                bf16x8 a = *(const bf16x8*)&Pt[wave * 16 + l15][kt * 32 + quad * 8];
                #pragma unroll
                for (int nt = 0; nt < 4; ++nt) {
                    bf16x8 b = *(const bf16x8*)&Vs[nt * 16 + l15][kt * 32 + quad * 8];
                    acc_o[nt] = __builtin_amdgcn_mfma_f32_16x16x32_bf16(a, b, acc_o[nt], 0, 0, 0);
                }
            }
        }

        // epilogue (per half): one cross-lane l reduction
        float l_r = (lsum[0] + lsum[1]) + (lsum[2] + lsum[3]);
        l_r += __shfl_xor(l_r, 16);
        l_r += __shfl_xor(l_r, 32);
        float linv[4];
        #pragma unroll
        for (int r = 0; r < 4; ++r) linv[r] = 1.0f / __shfl(l_r, quad * 4 + r);
        #pragma unroll
        for (int nt = 0; nt < 4; ++nt)
            #pragma unroll
            for (int r = 0; r < 4; ++r) {
                int row = q0 + wave * 16 + quad * 4 + r;
                O[(size_t)row * DM + h * HD + nt * 16 + l15] = f2bf(acc_o[nt][r] * linv[r]);
            }
    }
}

// ---------------------------------------------------------------------------
extern "C" void kernel_launch(void* const* d_in, const int* in_sizes, int n_in,
                              void* d_out, int out_size, void* d_ws, size_t ws_size,
                              hipStream_t stream) {
    const void* x  = d_in[0];
    const void* wq = d_in[1];
    const void* wk = d_in[2];
    const void* wv = d_in[3];
    const void* wo = d_in[4];

    const size_t SZ = (size_t)L_SEQ * DM;   // 4M elems
    const size_t WZ = (size_t)DM * DM;      // 1M elems
    ushort_t* xb = (ushort_t*)d_ws;         // 8 MB
    ushort_t* wT = xb + SZ;                 // 4 x 2 MB
    ushort_t* Qp = wT + 4 * WZ;             // 8 MB
    ushort_t* Kp = Qp + SZ;                 // 8 MB
    ushort_t* Vp = Kp + SZ;                 // 8 MB
    ushort_t* Vt = Vp + SZ;                 // 8 MB  -> total 48 MB
    ushort_t* An = xb;                      // xb dead after qkv -> safe alias

    convert_x<<<2048, 256, 0, stream>>>(x, xb);
    convert_wt<<<dim3(16, 16, 4), 256, 0, stream>>>(x, wq, wk, wv, wo, wT);
    qkv128<<<dim3(DM / 128, L_SEQ / 128, 3), 256, 0, stream>>>(xb, wT, Qp, Kp, Vp);
    transpose_kernel<<<dim3(L_SEQ / 64, DM / 64), 256, 0, stream>>>(Vp, Vt);
    attn_kernel<<<dim3(32, NH), 256, 0, stream>>>(Qp, Kp, Vt, An);
    ogemm128<<<dim3(DM / 128, L_SEQ / 128), 256, 0, stream>>>(x, An, wT + 3 * WZ, d_out);
}

// Round 8
// 300.569 us; speedup vs baseline: 1.1720x; 1.1194x over previous
//
#include <hip/hip_runtime.h>

#define L_SEQ 4096
#define DM    1024
#define NH    16
#define HD    64

typedef unsigned short ushort_t;
typedef __attribute__((ext_vector_type(8))) short bf16x8;
typedef __attribute__((ext_vector_type(4))) float f32x4;

__device__ inline unsigned short f2bf(float f) {
    union { float f; unsigned int u; } v; v.f = f;
    unsigned int r = v.u + 0x7fffu + ((v.u >> 16) & 1u);
    return (unsigned short)(r >> 16);
}

// async global->LDS, 16B/lane. LDS dest = wave-uniform base + lane*16.
__device__ inline void load_lds16(const ushort_t* g, ushort_t* l) {
    __builtin_amdgcn_global_load_lds(
        (const __attribute__((address_space(1))) unsigned int*)g,
        (__attribute__((address_space(3))) unsigned int*)l, 16, 0, 0);
}

// ---------------------------------------------------------------------------
// Runtime input-dtype detection (bf16 vs fp32 global buffers). Verified R3.
// ---------------------------------------------------------------------------
__device__ inline bool detect_f32(const ushort_t* xraw) {
    __shared__ int s_flag;
    const int t = threadIdx.x;
    if (t < 64) {
        unsigned e = (xraw[2 * t] >> 7) & 0xFFu;
        unsigned long long m = __ballot(e >= 0x88u);
        if (t == 0) s_flag = (__popcll(m) >= 8) ? 1 : 0;
    }
    __syncthreads();
    return s_flag != 0;
}

// ---------------------------------------------------------------------------
// x -> bf16 canonical buffer (4M elems, 8 elems/thread)
// ---------------------------------------------------------------------------
__global__ __launch_bounds__(256) void convert_x(const void* __restrict__ xv,
                                                 ushort_t* __restrict__ xb) {
    bool f32 = detect_f32((const ushort_t*)xv);
    const int i = (blockIdx.x * 256 + threadIdx.x) * 8;
    if (f32) {
        const float* xf = (const float*)xv;
        float4 v0 = *(const float4*)(xf + i);
        float4 v1 = *(const float4*)(xf + i + 4);
        ushort_t pk[8] = {f2bf(v0.x), f2bf(v0.y), f2bf(v0.z), f2bf(v0.w),
                          f2bf(v1.x), f2bf(v1.y), f2bf(v1.z), f2bf(v1.w)};
        *(uint4*)(xb + i) = *(const uint4*)pk;
    } else {
        *(uint4*)(xb + i) = *(const uint4*)((const ushort_t*)xv + i);
    }
}

// ---------------------------------------------------------------------------
// weights -> bf16 TRANSPOSED wT[n][k] (z picks which of 4 weights)
// ---------------------------------------------------------------------------
__global__ __launch_bounds__(256) void convert_wt(const void* __restrict__ xdet,
                                                  const void* __restrict__ w0,
                                                  const void* __restrict__ w1,
                                                  const void* __restrict__ w2,
                                                  const void* __restrict__ w3,
                                                  ushort_t* __restrict__ wT) {
    bool f32 = detect_f32((const ushort_t*)xdet);
    const int z = blockIdx.z;
    const void* w = (z == 0) ? w0 : (z == 1) ? w1 : (z == 2) ? w2 : w3;
    ushort_t* out = wT + (size_t)z * (DM * DM);
    __shared__ ushort_t T[64][65];
    const int k0 = blockIdx.x * 64, n0 = blockIdx.y * 64;
    const int t = threadIdx.x;
    #pragma unroll
    for (int i = 0; i < 16; ++i) {
        int e = t + i * 256;
        int r = e >> 6, c = e & 63;
        T[r][c] = f32 ? f2bf(((const float*)w)[(size_t)(k0 + r) * DM + n0 + c])
                      : ((const ushort_t*)w)[(size_t)(k0 + r) * DM + n0 + c];
    }
    __syncthreads();
    #pragma unroll
    for (int i = 0; i < 16; ++i) {
        int e = t + i * 256;
        int d = e >> 6, l = e & 63;
        out[(size_t)(n0 + d) * DM + k0 + l] = T[l][d];
    }
}

// ---------------------------------------------------------------------------
// m97-structure GEMM: C[M,1024] = A[M,1024] * Bt[1024,1024]^T (Bt is [n][k]).
// 128x128 tile, BK=32, 256 thr. Both operands staged via global_load_lds x16.
// ---------------------------------------------------------------------------
__device__ inline void gemm128_body(const ushort_t* __restrict__ A,
                                    const ushort_t* __restrict__ Bt,
                                    void* __restrict__ Cv, bool c_f32) {
    constexpr int K = 1024, NOUT = 1024;
    __shared__ ushort_t As[128 * 32];
    __shared__ ushort_t Bs[128 * 32];

    const int t = threadIdx.x, lane = t & 63, wave = t >> 6;
    const int l15 = lane & 15, quad = lane >> 4;
    const int m0 = blockIdx.y * 128, n0 = blockIdx.x * 128;
    const int mw = (wave >> 1) * 64, nw = (wave & 1) * 64;
    const int srow = lane >> 2, scol = (lane & 3) * 8;

    f32x4 acc[4][4] = {};

    for (int k0 = 0; k0 < K; k0 += 32) {
        #pragma unroll
        for (int j = 0; j < 2; ++j) {
            const int r0 = wave * 32 + j * 16;
            load_lds16(A  + (size_t)(m0 + r0 + srow) * K + k0 + scol, &As[r0 * 32]);
            load_lds16(Bt + (size_t)(n0 + r0 + srow) * K + k0 + scol, &Bs[r0 * 32]);
        }
        __syncthreads();

        bf16x8 af[4], bf[4];
        #pragma unroll
        for (int i = 0; i < 4; ++i) {
            af[i] = *(const bf16x8*)&As[(mw + i * 16 + l15) * 32 + quad * 8];
            bf[i] = *(const bf16x8*)&Bs[(nw + i * 16 + l15) * 32 + quad * 8];
        }
        #pragma unroll
        for (int mt = 0; mt < 4; ++mt)
            #pragma unroll
            for (int nt = 0; nt < 4; ++nt)
                acc[mt][nt] = __builtin_amdgcn_mfma_f32_16x16x32_bf16(af[mt], bf[nt], acc[mt][nt], 0, 0, 0);

        __syncthreads();
    }

    ushort_t* Ch = (ushort_t*)Cv;
    float*    Cf = (float*)Cv;
    #pragma unroll
    for (int mt = 0; mt < 4; ++mt)
        #pragma unroll
        for (int nt = 0; nt < 4; ++nt)
            #pragma unroll
            for (int r = 0; r < 4; ++r) {
                int row = m0 + mw + mt * 16 + quad * 4 + r;
                int col = n0 + nw + nt * 16 + l15;
                if (c_f32) Cf[(size_t)row * NOUT + col] = acc[mt][nt][r];
                else       Ch[(size_t)row * NOUT + col] = f2bf(acc[mt][nt][r]);
            }
}

__global__ __launch_bounds__(256) void qkv128(const ushort_t* __restrict__ xb,
                                              const ushort_t* __restrict__ wT,
                                              ushort_t* Qp, ushort_t* Kp, ushort_t* Vp) {
    const int z = blockIdx.z;
    const ushort_t* Bt = wT + (size_t)z * (DM * DM);
    ushort_t* C = (z == 0) ? Qp : (z == 1) ? Kp : Vp;
    gemm128_body(xb, Bt, C, false);
}

__global__ __launch_bounds__(256) void ogemm128(const void* __restrict__ xdet,
                                                const ushort_t* __restrict__ An,
                                                const ushort_t* __restrict__ woT,
                                                void* __restrict__ C) {
    bool f32 = detect_f32((const ushort_t*)xdet);
    gemm128_body(An, woT, C, f32);
}

// ---------------------------------------------------------------------------
// V transpose: Vp[L][DM] -> Vt[DM][L]
// ---------------------------------------------------------------------------
__global__ __launch_bounds__(256) void transpose_kernel(const ushort_t* __restrict__ Vp,
                                                        ushort_t* __restrict__ Vt) {
    __shared__ ushort_t T[64][65];
    const int l0 = blockIdx.x * 64, d0 = blockIdx.y * 64;
    const int t  = threadIdx.x;
    #pragma unroll
    for (int i = 0; i < 16; ++i) {
        int e = t + i * 256;
        int r = e >> 6, c = e & 63;
        T[r][c] = Vp[(size_t)(l0 + r) * DM + d0 + c];
    }
    __syncthreads();
    #pragma unroll
    for (int i = 0; i < 16; ++i) {
        int e = t + i * 256;
        int d = e >> 6, l = e & 63;
        Vt[(size_t)(d0 + d) * L_SEQ + l0 + l] = T[l][d];
    }
}

// ---------------------------------------------------------------------------
// Flash attention, S^T formulation. EXACT R5 softmax/structure (verified
// 123 us: online max, per-stage reductions, paired uniform blocks of 33
// stages). R8 changes ONLY the staging + block->head mapping:
//  (1) K/V staged via async global_load_lds (16B/lane) into UNPADDED LDS
//      with XOR granule swizzle (phys_granule = logical ^ (row&7)); swizzle
//      applied to the SOURCE address at staging (coalescing preserved:
//      permutation within 128B rows) and at fragment reads (loop-invariant).
//      Removes the global->VGPR->ds_write round trip from the stage path.
//  (2) XCD-locality decode: h = 2*(b&7) + ((b>>3)&1), bx = b>>4 -> each XCD
//      (round-robin over blockIdx) sees only 2 heads => K+V 2MB fits its L2.
// ---------------------------------------------------------------------------
__global__ __launch_bounds__(256) void attn_kernel(const ushort_t* __restrict__ Q,
                                                   const ushort_t* __restrict__ Kp,
                                                   const ushort_t* __restrict__ Vt,
                                                   ushort_t* __restrict__ O) {
    __shared__ ushort_t Ks[128 * 64];   // [kv][d], swizzled, 16 KB
    __shared__ ushort_t Vs[64 * 128];   // [d][kv], swizzled, 16 KB
    __shared__ ushort_t Pt[64][136];    // [q][kv], padded (VALU-written), 17 KB

    const int b    = blockIdx.x;               // 0..511
    const int h    = 2 * (b & 7) + ((b >> 3) & 1);
    const int bx   = b >> 4;                   // 0..31
    const int t    = threadIdx.x;
    const int lane = t & 63, wave = t >> 6;
    const int l15  = lane & 15, quad = lane >> 4;
    const float LOG2E  = 1.44269504f;
    const float slope2 = exp2f(-0.5f * (float)(h + 1)) * LOG2E;
    const float c0     = 0.125f * LOG2E;
    const float qd4f   = (float)(quad * 4);

    // staging lane constants (wave-uniform LDS bases + per-lane source addr)
    const int krow = lane >> 3, kgr = (lane & 7) ^ (lane >> 3);      // K slab
    const int vsub = lane >> 4;                                       // V slab

    // fragment-read swizzled offsets (loop-invariant)
    const int swz = l15 & 7;

    #pragma unroll
    for (int half = 0; half < 2; ++half) {
        const int qb = half ? bx : (63 - bx);
        const int q0 = qb * 64;
        const int qg = q0 + wave * 16 + l15;   // this lane's query row
        const float qf = (float)qg;

        bf16x8 bq[2];
        #pragma unroll
        for (int kt = 0; kt < 2; ++kt)
            bq[kt] = *(const bf16x8*)(Q + (size_t)qg * DM + h * HD + kt * 32 + quad * 8);

        f32x4 acc_o[4] = {};
        float m2 = -1e30f, l_r = 0.f;

        const int nst = (qb + 2) >> 1;
        for (int s = 0; s < nst; ++s) {
            const int kv0 = s * 128;
            __syncthreads();   // prior-stage Ks/Vs/Pt reads complete

            // K: 128 rows x 64d, 16 x (1KB = 8 rows); j = wave*4+i
            #pragma unroll
            for (int i = 0; i < 4; ++i) {
                const int j = wave * 4 + i;
                const int r = 8 * j + krow;
                load_lds16(Kp + (size_t)(kv0 + r) * DM + h * HD + kgr * 8,
                           &Ks[8 * j * 64]);
            }
            // V^T: 64 rows x 128kv, 16 x (1KB = 4 rows); d&7 = 4*(j&1)+vsub
            #pragma unroll
            for (int i = 0; i < 4; ++i) {
                const int j = wave * 4 + i;
                const int d = 4 * j + vsub;
                const int g = (lane & 15) ^ (4 * (j & 1) + vsub);
                load_lds16(Vt + (size_t)(h * HD + d) * L_SEQ + kv0 + g * 8,
                           &Vs[4 * j * 128]);
            }
            __syncthreads();   // drains vmcnt before fragment reads

            // S^T[kv][q]: A = K (m=kv), B = Q (n=q). Lane: q=l15, kv=mt*16+quad*4+r
            f32x4 sacc[8];
            #pragma unroll
            for (int mt = 0; mt < 8; ++mt) sacc[mt] = (f32x4){0.f, 0.f, 0.f, 0.f};
            #pragma unroll
            for (int kt = 0; kt < 2; ++kt)
                #pragma unroll
                for (int mt = 0; mt < 8; ++mt) {
                    bf16x8 a = *(const bf16x8*)&Ks[(mt * 16 + l15) * 64
                                                   + (((kt * 4 + quad) ^ swz) * 8)];
                    sacc[mt] = __builtin_amdgcn_mfma_f32_16x16x32_bf16(a, bq[kt], sacc[mt], 0, 0, 0);
                }

            // scores: /sqrt(hd) + alibi (log2 domain), causal mask on diag stage
            const bool diag = (kv0 + 128 > q0);
            const float off = slope2 * ((float)kv0 + qd4f - qf);
            #pragma unroll
            for (int mt = 0; mt < 8; ++mt)
                #pragma unroll
                for (int r = 0; r < 4; ++r) {
                    float kvl = (float)(mt * 16 + r);
                    float s2  = fmaf(sacc[mt][r], c0, fmaf(slope2, kvl, off));
                    if (diag) {
                        int kvg = kv0 + mt * 16 + quad * 4 + r;
                        s2 = (kvg <= qg) ? s2 : -1e30f;
                    }
                    sacc[mt][r] = s2;
                }

            // online softmax: in-register row max + quad-combine
            float mx = sacc[0][0];
            #pragma unroll
            for (int mt = 0; mt < 8; ++mt)
                #pragma unroll
                for (int r = 0; r < 4; ++r) mx = fmaxf(mx, sacc[mt][r]);
            mx = fmaxf(mx, __shfl_xor(mx, 16));
            mx = fmaxf(mx, __shfl_xor(mx, 32));
            float m_new = fmaxf(m2, mx);
            float alpha = exp2f(m2 - m_new);
            m2 = m_new;

            float rs = 0.f;
            #pragma unroll
            for (int mt = 0; mt < 8; ++mt)
                #pragma unroll
                for (int r = 0; r < 4; ++r) {
                    float p = exp2f(sacc[mt][r] - m2);
                    sacc[mt][r] = p;
                    rs += p;
                }
            rs += __shfl_xor(rs, 16);
            rs += __shfl_xor(rs, 32);
            l_r = l_r * alpha + rs;

            float alpha_row[4];
            #pragma unroll
            for (int r = 0; r < 4; ++r) alpha_row[r] = __shfl(alpha, quad * 4 + r);
            #pragma unroll
            for (int nt = 0; nt < 4; ++nt)
                #pragma unroll
                for (int r = 0; r < 4; ++r) acc_o[nt][r] *= alpha_row[r];

            // pack P^T -> Pt[q][kv] (b64 truncation pack)
            #pragma unroll
            for (int mt = 0; mt < 8; ++mt) {
                union { float f; unsigned u; } a0, a1, a2, a3;
                a0.f = sacc[mt][0]; a1.f = sacc[mt][1];
                a2.f = sacc[mt][2]; a3.f = sacc[mt][3];
                uint2 w;
                w.x = __builtin_amdgcn_perm(a1.u, a0.u, 0x07060302);
                w.y = __builtin_amdgcn_perm(a3.u, a2.u, 0x07060302);
                *(uint2*)&Pt[wave * 16 + l15][mt * 16 + quad * 4] = w;
            }
            __threadfence_block();   // wave-private Pt rows: order writes/reads

            // O += P·V: A = Pt[q][kv], B = Vs[d][kv] (swizzled)
            #pragma unroll
            for (int kt = 0; kt < 4; ++kt) {
                bf16x8 a = *(const bf16x8*)&Pt[wave * 16 + l15][kt * 32 + quad * 8];
                #pragma unroll
                for (int nt = 0; nt < 4; ++nt) {
                    bf16x8 bvv = *(const bf16x8*)&Vs[(nt * 16 + l15) * 128
                                                     + (((kt * 4 + quad) ^ swz) * 8)];
                    acc_o[nt] = __builtin_amdgcn_mfma_f32_16x16x32_bf16(a, bvv, acc_o[nt], 0, 0, 0);
                }
            }
        }

        // epilogue (per half)
        float linv[4];
        #pragma unroll
        for (int r = 0; r < 4; ++r) linv[r] = 1.0f / __shfl(l_r, quad * 4 + r);
        #pragma unroll
        for (int nt = 0; nt < 4; ++nt)
            #pragma unroll
            for (int r = 0; r < 4; ++r) {
                int row = q0 + wave * 16 + quad * 4 + r;
                O[(size_t)row * DM + h * HD + nt * 16 + l15] = f2bf(acc_o[nt][r] * linv[r]);
            }
    }
}

// ---------------------------------------------------------------------------
extern "C" void kernel_launch(void* const* d_in, const int* in_sizes, int n_in,
                              void* d_out, int out_size, void* d_ws, size_t ws_size,
                              hipStream_t stream) {
    const void* x  = d_in[0];
    const void* wq = d_in[1];
    const void* wk = d_in[2];
    const void* wv = d_in[3];
    const void* wo = d_in[4];

    const size_t SZ = (size_t)L_SEQ * DM;   // 4M elems
    const size_t WZ = (size_t)DM * DM;      // 1M elems
    ushort_t* xb = (ushort_t*)d_ws;         // 8 MB
    ushort_t* wT = xb + SZ;                 // 4 x 2 MB
    ushort_t* Qp = wT + 4 * WZ;             // 8 MB
    ushort_t* Kp = Qp + SZ;                 // 8 MB
    ushort_t* Vp = Kp + SZ;                 // 8 MB
    ushort_t* Vt = Vp + SZ;                 // 8 MB  -> total 48 MB
    ushort_t* An = xb;                      // xb dead after qkv -> safe alias

    convert_x<<<2048, 256, 0, stream>>>(x, xb);
    convert_wt<<<dim3(16, 16, 4), 256, 0, stream>>>(x, wq, wk, wv, wo, wT);
    qkv128<<<dim3(DM / 128, L_SEQ / 128, 3), 256, 0, stream>>>(xb, wT, Qp, Kp, Vp);
    transpose_kernel<<<dim3(L_SEQ / 64, DM / 64), 256, 0, stream>>>(Vp, Vt);
    attn_kernel<<<512, 256, 0, stream>>>(Qp, Kp, Vt, An);
    ogemm128<<<dim3(DM / 128, L_SEQ / 128), 256, 0, stream>>>(x, An, wT + 3 * WZ, d_out);
}